// Round 7
// baseline (168.292 us; speedup 1.0000x reference)
//
#include <hip/hip_runtime.h>
#include <hip/hip_bf16.h>
#include <stdint.h>

// Problem constants
#define B_   8
#define S_   2048
#define D_   1280
#define OUT_ 1280
#define K_   (2 * D_)     // 2560
#define M_   (B_ * S_)    // 16384

// GEMM geometry: 256x160 tile, BK=32, 4 waves of 128x80, grid 512 (2 blocks/CU)
#define BM    256
#define BN    160
#define BK    32
#define NKT   (K_ / BK)        // 80
#define AT_E  (BM * BK)        // 8192 elems (16 KB) per A K-tile
#define BT_E  (BN * BK)        // 5120 elems (10 KB) per B K-tile
#define BUF_E (AT_E + BT_E)    // 13312 elems = 26 KB per LDS buffer
#define NCH   26               // 1KB staging chunks per buffer (16 A + 10 B)
#define NMT   (M_ / BM)        // 64
#define NNT   (OUT_ / BN)      // 8

typedef __bf16 bf16_t;
typedef bf16_t bf16x8 __attribute__((ext_vector_type(8)));
typedef float  f32x4  __attribute__((ext_vector_type(4)));

// ---------------------------------------------------------------------------
// lengths: per-batch valid count (prefix mask). Handles byte or int32 storage.
// ---------------------------------------------------------------------------
__global__ void lengths_kernel(const unsigned char* __restrict__ mask,
                               int* __restrict__ len) {
    const int b = blockIdx.x;
    const bool bytefmt = (mask[1] != 0);   // lengths >= 512 so elem 1 is true
    int cnt = 0;
    if (bytefmt) {
        for (int s = threadIdx.x; s < S_; s += blockDim.x)
            cnt += (mask[(size_t)b * S_ + s] != 0) ? 1 : 0;
    } else {
        const int* mi = (const int*)mask;
        for (int s = threadIdx.x; s < S_; s += blockDim.x)
            cnt += (mi[(size_t)b * S_ + s] != 0) ? 1 : 0;
    }
    #pragma unroll
    for (int off = 32; off > 0; off >>= 1) cnt += __shfl_down(cnt, off);
    __shared__ int wsum[4];
    const int wid = threadIdx.x >> 6;
    if ((threadIdx.x & 63) == 0) wsum[wid] = cnt;
    __syncthreads();
    if (threadIdx.x == 0) len[b] = wsum[0] + wsum[1] + wsum[2] + wsum[3];
}

__device__ inline bf16x8 cvt8(float4 x, float4 y) {
    bf16x8 r;
    r[0] = (bf16_t)x.x; r[1] = (bf16_t)x.y; r[2] = (bf16_t)x.z; r[3] = (bf16_t)x.w;
    r[4] = (bf16_t)y.x; r[5] = (bf16_t)y.y; r[6] = (bf16_t)y.z; r[7] = (bf16_t)y.w;
    return r;
}

// ---------------------------------------------------------------------------
// Pack A (coalesced): f32 -> bf16, fused masked-reverse gather,
// [64 mt][80 kt][256r x 32k] tiles. Chunk c (8 bf16) of row r stored at slot
// (c ^ ((r>>1)&3)): elem offset r*32 + slot*8.
// Thread map: c = tid&3, r = (tid>>2) + 64p -> 16 rows x 128 B per wave instr.
// ---------------------------------------------------------------------------
__global__ __launch_bounds__(256) void pack_a4_kernel(
    const float* __restrict__ fwd, const float* __restrict__ rev,
    const int* __restrict__ len, bf16_t* __restrict__ packA) {
    const int kt = blockIdx.x;            // 0..79
    const int mt = blockIdx.y;            // 0..63
    const int b  = mt >> 3;               // 8 m-tiles (256 rows) per batch
    const int n  = len[b];
    const int c  = threadIdx.x & 3;       // k-chunk (8 f32 = 32 B)
    const int r0 = threadIdx.x >> 2;      // 0..63
    const int kk = kt * BK + c * 8;       // global k for this chunk
    bf16_t* dst = packA + ((size_t)mt * NKT + kt) * AT_E;
    #pragma unroll
    for (int p = 0; p < 4; ++p) {
        const int r = r0 + p * 64;
        const int s = (mt & 7) * 256 + r;
        const float* src;
        if (kk < D_) {
            src = fwd + (size_t)(b * S_ + s) * D_ + kk;
        } else {
            const int ss = (s < n) ? (n - 1 - s) : s;
            src = rev + (size_t)(b * S_ + ss) * D_ + (kk - D_);
        }
        float4 x = *(const float4*)src;
        float4 y = *(const float4*)(src + 4);
        const int slot = c ^ ((r >> 1) & 3);
        *(bf16x8*)(dst + r * BK + slot * 8) = cvt8(x, y);
    }
}

// Pack W (coalesced, same mapping): [8 nt][80 kt][160r x 32k] tiles.
__global__ __launch_bounds__(320) void pack_w5_kernel(
    const float* __restrict__ W, bf16_t* __restrict__ packW) {
    const int kt = blockIdx.x;            // 0..79
    const int nt = blockIdx.y;            // 0..7
    const int c  = threadIdx.x & 3;
    const int r0 = threadIdx.x >> 2;      // 0..79
    const int kk = kt * BK + c * 8;
    bf16_t* dst = packW + ((size_t)nt * NKT + kt) * BT_E;
    #pragma unroll
    for (int p = 0; p < 2; ++p) {
        const int r = r0 + p * 80;        // 0..159
        const float* src = W + (size_t)(nt * BN + r) * K_ + kk;
        float4 x = *(const float4*)src;
        float4 y = *(const float4*)(src + 4);
        const int slot = c ^ ((r >> 1) & 3);
        *(bf16x8*)(dst + r * BK + slot * 8) = cvt8(x, y);
    }
}

// ---------------------------------------------------------------------------
// GEMM: 256x160 tile, 4 waves (2M x 2N, 128x80 each), BK=32, 3-deep LDS
// buffers (78 KB -> 2 blocks/CU), global_load_lds staging of tile t+2 during
// compute of t, per-wave counted vmcnt, ONE barrier per K-tile.
// Two independent blocks per CU = two barrier domains per SIMD: when one
// block's wave is in its MFMA cluster the other's can issue ds_reads ->
// LDS pipe and matrix pipe overlap (the round-5/6 serialization fix).
// ---------------------------------------------------------------------------
#define GLL(gp, lp) __builtin_amdgcn_global_load_lds(                        \
    (const __attribute__((address_space(1))) unsigned int*)(const void*)(gp),\
    (__attribute__((address_space(3))) unsigned int*)(void*)(lp), 16, 0, 0)

__global__ __launch_bounds__(256, 2) void gemm11_kernel(
    const bf16_t* __restrict__ pA, const bf16_t* __restrict__ pW,
    const float* __restrict__ bias, float* __restrict__ out) {

    __shared__ __align__(16) bf16_t lds[3 * BUF_E];   // 79872 B

    // XCD swizzle: 512 blocks = 8 XCDs x 64; XCD x gets rt in [8x, 8x+8),
    // all 8 ct's of an rt-panel stay on one XCD (A-panel L2 reuse).
    const int bid = blockIdx.x;
    const int swz = (bid & 7) * 64 + (bid >> 3);
    const int rt  = swz >> 3;             // 0..63
    const int ct  = swz & 7;              // 0..7

    const int t  = threadIdx.x;
    const int l  = t & 63;
    const int w  = t >> 6;                // 0..3
    const int wm = w >> 1;                // 0..1  (128-row group)
    const int wn = w & 1;                 // 0..1  (80-col group)

    const bf16_t* gA = pA + (size_t)rt * NKT * AT_E;
    const bf16_t* gB = pW + (size_t)ct * NKT * BT_E;

    const int l8 = l * 8;

    // fragment offsets: row = (wm*128|wn*80) + {i|j}*16 + lrow, chunk c = l>>4,
    // slot = c ^ ((row>>1)&3) = c ^ ((lrow>>1)&3)  (panel/frag offsets = 0 mod 4)
    const int lrow = l & 15;
    const int slot = (l >> 4) ^ ((lrow >> 1) & 3);
    const int aoff = (wm * 128 + lrow) * BK + slot * 8;
    const int boff = AT_E + (wn * 80 + lrow) * BK + slot * 8;

    f32x4 acc[8][5] = {};

    // staging: 26 x 1KB chunks per tile; wave w takes {w, w+4, w+8, ...}:
    // 7 chunks for w<2, 6 for w>=2. Chunk cc<16 -> A at elem cc*512,
    // cc>=16 -> B at elem cc*512 - AT_E. LDS dest is linear (rule 21).
    // ---- prologue: stage tiles 0 -> buf0, 1 -> buf1 ----
    #pragma unroll
    for (int p = 0; p < 2; ++p) {
        const bf16_t* at = gA + (size_t)p * AT_E;
        const bf16_t* bt = gB + (size_t)p * BT_E;
        const int ob = p * BUF_E;
        for (int cc = w; cc < NCH; cc += 4) {
            const int off = cc * 512;
            const bf16_t* src = (cc < 16) ? (at + off) : (bt + off - AT_E);
            GLL(src + l8, &lds[ob + off]);
        }
    }

    int o0 = 0, o1 = BUF_E, o2 = 2 * BUF_E;

    for (int kt = 0; kt < NKT; ++kt) {
        // boundary: own stage(kt) landed; stage(kt+1) (7 or 6 chunks) in flight
        if (kt + 1 < NKT) {
            if (w < 2) asm volatile("s_waitcnt vmcnt(7)" ::: "memory");
            else       asm volatile("s_waitcnt vmcnt(6)" ::: "memory");
        } else {
            asm volatile("s_waitcnt vmcnt(0)" ::: "memory");
        }
        __builtin_amdgcn_s_barrier();
        __builtin_amdgcn_sched_barrier(0);

        // issue stage(kt+2) into the buffer freed at kt-1
        if (kt + 2 < NKT) {
            const bf16_t* at = gA + (size_t)(kt + 2) * AT_E;
            const bf16_t* bt = gB + (size_t)(kt + 2) * BT_E;
            for (int cc = w; cc < NCH; cc += 4) {
                const int off = cc * 512;
                const bf16_t* src = (cc < 16) ? (at + off) : (bt + off - AT_E);
                GLL(src + l8, &lds[o2 + off]);
            }
        }

        bf16x8 af[8], bfr[5];
        #pragma unroll
        for (int i = 0; i < 8; ++i)
            af[i] = *(const bf16x8*)&lds[o0 + aoff + i * 512];
        #pragma unroll
        for (int j = 0; j < 5; ++j)
            bfr[j] = *(const bf16x8*)&lds[o0 + boff + j * 512];

        __builtin_amdgcn_s_setprio(1);
        #pragma unroll
        for (int i = 0; i < 8; ++i)
            #pragma unroll
            for (int j = 0; j < 5; ++j)
                acc[i][j] = __builtin_amdgcn_mfma_f32_16x16x32_bf16(
                    af[i], bfr[j], acc[i][j], 0, 0, 0);
        __builtin_amdgcn_s_setprio(0);

        const int tmp = o0; o0 = o1; o1 = o2; o2 = tmp;
    }

    // ---- epilogue: C/D layout col=lane&15, row=(lane>>4)*4+v ----
    const int m0 = rt * BM + wm * 128;
    const int n0 = ct * BN + wn * 80;
    const int r4 = (l >> 4) * 4;
    #pragma unroll
    for (int j = 0; j < 5; ++j) {
        const int col = n0 + j * 16 + lrow;
        const float bj = bias[col];
        #pragma unroll
        for (int i = 0; i < 8; ++i) {
            const int row0 = m0 + i * 16 + r4;
            #pragma unroll
            for (int v = 0; v < 4; ++v)
                out[(size_t)(row0 + v) * OUT_ + col] = acc[i][j][v] + bj;
        }
    }
}

// ---------------------------------------------------------------------------
// Fallback (round-1 kernel): used only if ws_size can't hold packed operands.
// ---------------------------------------------------------------------------
#define LDKF 40
__global__ __launch_bounds__(256) void profam_gemm_fallback(
    const float* __restrict__ fwd, const float* __restrict__ rev,
    const float* __restrict__ W,   const float* __restrict__ bias,
    const int* __restrict__ len,   float* __restrict__ out) {

    __shared__ __align__(16) bf16_t lds_a[128][LDKF];
    __shared__ __align__(16) bf16_t lds_b[128][LDKF];

    const int ct = blockIdx.x;
    const int rt = blockIdx.y;
    const int m0 = rt * 128;
    const int n0 = ct * 128;
    const int t  = threadIdx.x;
    const int l  = t & 63;
    const int w  = t >> 6;
    const int wr = w >> 1, wc = w & 1;

    const int b = m0 >> 11;
    const int n = len[b];

    const int sr = t >> 1;
    const int cg = (t & 1) * 16;
    const int s  = (m0 + sr) & (S_ - 1);
    const int ss = (s < n) ? (n - 1 - s) : s;
    const float* pf = fwd + (size_t)(b * S_ + s)  * D_ + cg;
    const float* pr = rev + (size_t)(b * S_ + ss) * D_ + cg;
    const float* pw = W   + (size_t)(n0 + sr) * K_ + cg;

    f32x4 acc[4][4] = {};
    const int lrow = l & 15;
    const int kc   = (l >> 4) * 8;

    for (int kt = 0; kt < K_ / 32; ++kt) {
        const int k0 = kt * 32;
        const float* pa = (k0 < D_) ? (pf + k0) : (pr + (k0 - D_));
        const float* pb = pw + k0;
        float4 a0 = *(const float4*)(pa + 0);
        float4 a1 = *(const float4*)(pa + 4);
        float4 a2 = *(const float4*)(pa + 8);
        float4 a3 = *(const float4*)(pa + 12);
        float4 b0 = *(const float4*)(pb + 0);
        float4 b1 = *(const float4*)(pb + 4);
        float4 b2 = *(const float4*)(pb + 8);
        float4 b3 = *(const float4*)(pb + 12);
        *(bf16x8*)&lds_a[sr][cg + 0] = cvt8(a0, a1);
        *(bf16x8*)&lds_a[sr][cg + 8] = cvt8(a2, a3);
        *(bf16x8*)&lds_b[sr][cg + 0] = cvt8(b0, b1);
        *(bf16x8*)&lds_b[sr][cg + 8] = cvt8(b2, b3);
        __syncthreads();
        bf16x8 af[4], bfr[4];
        #pragma unroll
        for (int i = 0; i < 4; ++i)
            af[i] = *(const bf16x8*)&lds_a[wr * 64 + i * 16 + lrow][kc];
        #pragma unroll
        for (int j = 0; j < 4; ++j)
            bfr[j] = *(const bf16x8*)&lds_b[wc * 64 + j * 16 + lrow][kc];
        #pragma unroll
        for (int i = 0; i < 4; ++i)
            #pragma unroll
            for (int j = 0; j < 4; ++j)
                acc[i][j] = __builtin_amdgcn_mfma_f32_16x16x32_bf16(
                    af[i], bfr[j], acc[i][j], 0, 0, 0);
        __syncthreads();
    }
    #pragma unroll
    for (int j = 0; j < 4; ++j) {
        const int col = n0 + wc * 64 + j * 16 + lrow;
        const float bj = bias[col];
        #pragma unroll
        for (int i = 0; i < 4; ++i) {
            const int row0 = m0 + wr * 64 + i * 16 + (l >> 4) * 4;
            #pragma unroll
            for (int v = 0; v < 4; ++v)
                out[(size_t)(row0 + v) * OUT_ + col] = acc[i][j][v] + bj;
        }
    }
}

extern "C" void kernel_launch(void* const* d_in, const int* in_sizes, int n_in,
                              void* d_out, int out_size, void* d_ws, size_t ws_size,
                              hipStream_t stream) {
    const float* fwd  = (const float*)d_in[0];
    const float* rev  = (const float*)d_in[1];
    const unsigned char* mask = (const unsigned char*)d_in[2];
    const float* W    = (const float*)d_in[3];
    const float* bias = (const float*)d_in[4];
    float* out = (float*)d_out;

    int* len = (int*)d_ws;                                    // 8 ints @ offset 0
    const size_t offA = 256;
    const size_t szA  = (size_t)NMT * NKT * AT_E * 2;         // 83.89 MB
    const size_t offW = offA + szA;
    const size_t szW  = (size_t)NNT * NKT * BT_E * 2;         // 6.55 MB
    const size_t need = offW + szW;

    lengths_kernel<<<dim3(B_), dim3(256), 0, stream>>>(mask, len);

    if (ws_size >= need) {
        bf16_t* packA = (bf16_t*)((char*)d_ws + offA);
        bf16_t* packW = (bf16_t*)((char*)d_ws + offW);
        pack_a4_kernel<<<dim3(NKT, NMT), dim3(256), 0, stream>>>(fwd, rev, len, packA);
        pack_w5_kernel<<<dim3(NKT, NNT), dim3(320), 0, stream>>>(W, packW);
        gemm11_kernel<<<dim3(NMT * NNT), dim3(256), 0, stream>>>(packA, packW, bias, out);
    } else {
        profam_gemm_fallback<<<dim3(OUT_ / 128, M_ / 128), dim3(256), 0, stream>>>(
            fwd, rev, W, bias, len, out);
    }
}

// Round 8
// 159.760 us; speedup vs baseline: 1.0534x; 1.0534x over previous
//
#include <hip/hip_runtime.h>
#include <hip/hip_bf16.h>
#include <stdint.h>

// Problem constants
#define B_   8
#define S_   2048
#define D_   1280
#define OUT_ 1280
#define K_   (2 * D_)     // 2560
#define M_   (B_ * S_)    // 16384

// GEMM geometry: 256x320 tile, BK=32, 8 waves of 128x80, grid 256 (1/CU)
#define BM    256
#define BN    320
#define BK    32
#define NKT   (K_ / BK)        // 80
#define AT_E  (BM * BK)        // 8192 elems (16 KB) per A K-tile
#define BT_E  (BN * BK)        // 10240 elems (20 KB) per B K-tile
#define BUF_E (AT_E + BT_E)    // 18432 elems = 36 KB per LDS buffer
#define NMT   (M_ / BM)        // 64
#define NNT   (OUT_ / BN)      // 4

typedef __bf16 bf16_t;
typedef bf16_t bf16x8 __attribute__((ext_vector_type(8)));
typedef float  f32x4  __attribute__((ext_vector_type(4)));

// ---------------------------------------------------------------------------
// lengths: per-batch valid count (prefix mask). Handles byte or int32 storage.
// ---------------------------------------------------------------------------
__global__ void lengths_kernel(const unsigned char* __restrict__ mask,
                               int* __restrict__ len) {
    const int b = blockIdx.x;
    const bool bytefmt = (mask[1] != 0);   // lengths >= 512 so elem 1 is true
    int cnt = 0;
    if (bytefmt) {
        for (int s = threadIdx.x; s < S_; s += blockDim.x)
            cnt += (mask[(size_t)b * S_ + s] != 0) ? 1 : 0;
    } else {
        const int* mi = (const int*)mask;
        for (int s = threadIdx.x; s < S_; s += blockDim.x)
            cnt += (mi[(size_t)b * S_ + s] != 0) ? 1 : 0;
    }
    #pragma unroll
    for (int off = 32; off > 0; off >>= 1) cnt += __shfl_down(cnt, off);
    __shared__ int wsum[4];
    const int wid = threadIdx.x >> 6;
    if ((threadIdx.x & 63) == 0) wsum[wid] = cnt;
    __syncthreads();
    if (threadIdx.x == 0) len[b] = wsum[0] + wsum[1] + wsum[2] + wsum[3];
}

__device__ inline bf16x8 cvt8(float4 x, float4 y) {
    bf16x8 r;
    r[0] = (bf16_t)x.x; r[1] = (bf16_t)x.y; r[2] = (bf16_t)x.z; r[3] = (bf16_t)x.w;
    r[4] = (bf16_t)y.x; r[5] = (bf16_t)y.y; r[6] = (bf16_t)y.z; r[7] = (bf16_t)y.w;
    return r;
}

// Pack W (coalesced): [4 nt][80 kt][320r x 32k] tiles; chunk c of row r at
// slot (c ^ ((r>>1)&3)), elem offset r*32 + slot*8.
__global__ __launch_bounds__(320) void pack_w4_kernel(
    const float* __restrict__ W, bf16_t* __restrict__ packW) {
    const int kt = blockIdx.x;            // 0..79
    const int nt = blockIdx.y;            // 0..3
    const int c  = threadIdx.x & 3;
    const int r0 = threadIdx.x >> 2;      // 0..79
    const int kk = kt * BK + c * 8;
    bf16_t* dst = packW + ((size_t)nt * NKT + kt) * BT_E;
    #pragma unroll
    for (int p = 0; p < 4; ++p) {
        const int r = r0 + p * 80;
        const float* src = W + (size_t)(nt * BN + r) * K_ + kk;
        float4 x = *(const float4*)src;
        float4 y = *(const float4*)(src + 4);
        const int slot = c ^ ((r >> 1) & 3);
        *(bf16x8*)(dst + r * BK + slot * 8) = cvt8(x, y);
    }
}

// ---------------------------------------------------------------------------
// Fused GEMM: A (f32, with masked-reverse gather) is reg-staged in-kernel:
// issue f32 loads for tile t+2 right after the boundary barrier (T14
// issue-early), cvt+ds_write after the MFMA cluster (write-late), so HBM
// latency hides under the MFMA phase. B comes from packed ws via
// global_load_lds. 3-deep LDS buffers, counted per-wave vmcnt, one barrier
// per K-tile. Schedule otherwise identical to round-5 gemm9.
// ---------------------------------------------------------------------------
#define GLL(gp, lp) __builtin_amdgcn_global_load_lds(                        \
    (const __attribute__((address_space(1))) unsigned int*)(const void*)(gp),\
    (__attribute__((address_space(3))) unsigned int*)(void*)(lp), 16, 0, 0)

__global__ __launch_bounds__(512, 1) void gemm12_kernel(
    const float* __restrict__ fwd, const float* __restrict__ rev,
    const bf16_t* __restrict__ pW, const int* __restrict__ len,
    const float* __restrict__ bias, float* __restrict__ out) {

    __shared__ __align__(16) bf16_t lds[3 * BUF_E];   // 108 KB

    // XCD swizzle: XCD x gets rt in [8x, 8x+8); all 4 cts of an rt-panel on
    // one XCD -> the 4x A re-read is L2-absorbed.
    const int bid = blockIdx.x;
    const int swz = (bid & 7) * 32 + (bid >> 3);
    const int rt  = swz >> 2;             // 0..63
    const int ct  = swz & 3;              // 0..3

    const int t  = threadIdx.x;
    const int l  = t & 63;
    const int w  = t >> 6;                // 0..7
    const int wm = w >> 1;                // 0..3 -> use 2x4 grid below
    const int wmm = w >> 2;               // 0..1  (128-row group)
    const int wn  = w & 3;                // 0..3  (80-col group)
    (void)wm;

    const bf16_t* gB = pW + (size_t)ct * NKT * BT_E;
    const int l8 = l * 8;

    // ---- A gather pointers: thread t owns row r = t>>1, k-half kh = (t&1)*16
    const int r  = t >> 1;                // 0..255
    const int kh = (t & 1) * 16;
    const int m  = rt * BM + r;
    const int b  = m >> 11;
    const int s  = m & (S_ - 1);
    const int n  = len[b];
    const int ss = (s < n) ? (n - 1 - s) : s;
    const float* pf = fwd + (size_t)(b * S_ + s)  * D_;        // + kk (k < D)
    const float* pr = rev + (size_t)(b * S_ + ss) * D_ - D_;   // + kk (k >= D)
    // A LDS write offsets: chunks c0 = (kh>>3), c0+1; slot = c ^ ((r>>1)&3)
    const int swr = (r >> 1) & 3;
    const int wo0 = r * BK + (((kh >> 3) + 0) ^ swr) * 8;
    const int wo1 = r * BK + (((kh >> 3) + 1) ^ swr) * 8;

    // fragment read offsets (round-5-verified)
    const int lrow = l & 15;
    const int slot = (l >> 4) ^ ((lrow >> 1) & 3);
    const int aoff = (wmm * 128 + lrow) * BK + slot * 8;
    const int boff = AT_E + (wn * 80 + lrow) * BK + slot * 8;

    f32x4 acc[8][5] = {};

    // ---- prologue: A(0)->buf0, A(1)->buf1 via reg+cvt; B(0),B(1) via GLL ----
    #pragma unroll
    for (int p = 0; p < 2; ++p) {
        const int kk = p * BK + kh;       // < D_ always (p<=1)
        const float* sp = pf + kk;
        float4 x0 = *(const float4*)(sp);
        float4 x1 = *(const float4*)(sp + 4);
        float4 x2 = *(const float4*)(sp + 8);
        float4 x3 = *(const float4*)(sp + 12);
        bf16_t* dst = &lds[p * BUF_E];
        *(bf16x8*)(dst + wo0) = cvt8(x0, x1);
        *(bf16x8*)(dst + wo1) = cvt8(x2, x3);
    }
    #pragma unroll
    for (int p = 0; p < 2; ++p) {
        const bf16_t* btile = gB + (size_t)p * BT_E;
        const int ob = p * BUF_E + AT_E;
        GLL(btile + (w + 0) * 512 + l8, &lds[ob + (w + 0) * 512]);
        GLL(btile + (w + 8) * 512 + l8, &lds[ob + (w + 8) * 512]);
        if (w < 4) GLL(btile + (w + 16) * 512 + l8, &lds[ob + (w + 16) * 512]);
    }
    // drain prologue ds_writes before first barrier (cross-wave visibility)
    asm volatile("s_waitcnt lgkmcnt(0)" ::: "memory");

    int o0 = 0, o1 = BUF_E, o2 = 2 * BUF_E;

    for (int kt = 0; kt < NKT; ++kt) {
        // boundary: own B(kt) GLLs landed; B(kt+1) (2 or 3 per wave) in flight
        if (kt + 1 < NKT) {
            if (w < 4) asm volatile("s_waitcnt vmcnt(3)" ::: "memory");
            else       asm volatile("s_waitcnt vmcnt(2)" ::: "memory");
        } else {
            asm volatile("s_waitcnt vmcnt(0)" ::: "memory");
        }
        __builtin_amdgcn_s_barrier();
        __builtin_amdgcn_sched_barrier(0);

        // T14 issue-early: A f32 loads for tile kt+2 (consumed after MFMAs)
        const bool st = (kt + 2 < NKT);
        float4 x0, x1, x2, x3;
        if (st) {
            const int kk = (kt + 2) * BK + kh;       // wave-uniform branch
            const float* sp = ((kk < D_) ? pf : pr) + kk;
            x0 = *(const float4*)(sp);
            x1 = *(const float4*)(sp + 4);
            x2 = *(const float4*)(sp + 8);
            x3 = *(const float4*)(sp + 12);
        }
        __builtin_amdgcn_sched_barrier(0);

        bf16x8 af[8], bfr[5];
        #pragma unroll
        for (int i = 0; i < 8; ++i)
            af[i] = *(const bf16x8*)&lds[o0 + aoff + i * 512];
        #pragma unroll
        for (int j = 0; j < 5; ++j)
            bfr[j] = *(const bf16x8*)&lds[o0 + boff + j * 512];

        __builtin_amdgcn_s_setprio(1);
        #pragma unroll
        for (int i = 0; i < 8; ++i)
            #pragma unroll
            for (int j = 0; j < 5; ++j)
                acc[i][j] = __builtin_amdgcn_mfma_f32_16x16x32_bf16(
                    af[i], bfr[j], acc[i][j], 0, 0, 0);
        __builtin_amdgcn_s_setprio(0);
        __builtin_amdgcn_sched_barrier(0);

        // write-late: cvt + ds_write A(kt+2), then issue GLL B(kt+2)
        if (st) {
            bf16_t* dst = &lds[o2];
            *(bf16x8*)(dst + wo0) = cvt8(x0, x1);
            *(bf16x8*)(dst + wo1) = cvt8(x2, x3);
            const bf16_t* btile = gB + (size_t)(kt + 2) * BT_E;
            GLL(btile + (w + 0) * 512 + l8, &lds[o2 + AT_E + (w + 0) * 512]);
            GLL(btile + (w + 8) * 512 + l8, &lds[o2 + AT_E + (w + 8) * 512]);
            if (w < 4)
                GLL(btile + (w + 16) * 512 + l8, &lds[o2 + AT_E + (w + 16) * 512]);
        }

        const int tmp = o0; o0 = o1; o1 = o2; o2 = tmp;
    }

    // ---- epilogue: C/D layout col=lane&15, row=(lane>>4)*4+v ----
    const int m0 = rt * BM + wmm * 128;
    const int n0 = ct * BN + wn * 80;
    const int r4 = (l >> 4) * 4;
    #pragma unroll
    for (int j = 0; j < 5; ++j) {
        const int col = n0 + j * 16 + lrow;
        const float bj = bias[col];
        #pragma unroll
        for (int i = 0; i < 8; ++i) {
            const int row0 = m0 + i * 16 + r4;
            #pragma unroll
            for (int v = 0; v < 4; ++v)
                out[(size_t)(row0 + v) * OUT_ + col] = acc[i][j][v] + bj;
        }
    }
}

// ---------------------------------------------------------------------------
// Fallback (round-1 kernel): used only if ws_size can't hold packed W.
// ---------------------------------------------------------------------------
#define LDKF 40
__global__ __launch_bounds__(256) void profam_gemm_fallback(
    const float* __restrict__ fwd, const float* __restrict__ rev,
    const float* __restrict__ W,   const float* __restrict__ bias,
    const int* __restrict__ len,   float* __restrict__ out) {

    __shared__ __align__(16) bf16_t lds_a[128][LDKF];
    __shared__ __align__(16) bf16_t lds_b[128][LDKF];

    const int ct = blockIdx.x;
    const int rt = blockIdx.y;
    const int m0 = rt * 128;
    const int n0 = ct * 128;
    const int t  = threadIdx.x;
    const int l  = t & 63;
    const int w  = t >> 6;
    const int wr = w >> 1, wc = w & 1;

    const int b = m0 >> 11;
    const int n = len[b];

    const int sr = t >> 1;
    const int cg = (t & 1) * 16;
    const int s  = (m0 + sr) & (S_ - 1);
    const int ss = (s < n) ? (n - 1 - s) : s;
    const float* pf = fwd + (size_t)(b * S_ + s)  * D_ + cg;
    const float* pr = rev + (size_t)(b * S_ + ss) * D_ + cg;
    const float* pw = W   + (size_t)(n0 + sr) * K_ + cg;

    f32x4 acc[4][4] = {};
    const int lrow = l & 15;
    const int kc   = (l >> 4) * 8;

    for (int kt = 0; kt < K_ / 32; ++kt) {
        const int k0 = kt * 32;
        const float* pa = (k0 < D_) ? (pf + k0) : (pr + (k0 - D_));
        const float* pb = pw + k0;
        float4 a0 = *(const float4*)(pa + 0);
        float4 a1 = *(const float4*)(pa + 4);
        float4 a2 = *(const float4*)(pa + 8);
        float4 a3 = *(const float4*)(pa + 12);
        float4 b0 = *(const float4*)(pb + 0);
        float4 b1 = *(const float4*)(pb + 4);
        float4 b2 = *(const float4*)(pb + 8);
        float4 b3 = *(const float4*)(pb + 12);
        *(bf16x8*)&lds_a[sr][cg + 0] = cvt8(a0, a1);
        *(bf16x8*)&lds_a[sr][cg + 8] = cvt8(a2, a3);
        *(bf16x8*)&lds_b[sr][cg + 0] = cvt8(b0, b1);
        *(bf16x8*)&lds_b[sr][cg + 8] = cvt8(b2, b3);
        __syncthreads();
        bf16x8 af[4], bfr[4];
        #pragma unroll
        for (int i = 0; i < 4; ++i)
            af[i] = *(const bf16x8*)&lds_a[wr * 64 + i * 16 + lrow][kc];
        #pragma unroll
        for (int j = 0; j < 4; ++j)
            bfr[j] = *(const bf16x8*)&lds_b[wc * 64 + j * 16 + lrow][kc];
        #pragma unroll
        for (int i = 0; i < 4; ++i)
            #pragma unroll
            for (int j = 0; j < 4; ++j)
                acc[i][j] = __builtin_amdgcn_mfma_f32_16x16x32_bf16(
                    af[i], bfr[j], acc[i][j], 0, 0, 0);
        __syncthreads();
    }
    #pragma unroll
    for (int j = 0; j < 4; ++j) {
        const int col = n0 + wc * 64 + j * 16 + lrow;
        const float bj = bias[col];
        #pragma unroll
        for (int i = 0; i < 4; ++i) {
            const int row0 = m0 + wr * 64 + i * 16 + (l >> 4) * 4;
            #pragma unroll
            for (int v = 0; v < 4; ++v)
                out[(size_t)(row0 + v) * OUT_ + col] = acc[i][j][v] + bj;
        }
    }
}

extern "C" void kernel_launch(void* const* d_in, const int* in_sizes, int n_in,
                              void* d_out, int out_size, void* d_ws, size_t ws_size,
                              hipStream_t stream) {
    const float* fwd  = (const float*)d_in[0];
    const float* rev  = (const float*)d_in[1];
    const unsigned char* mask = (const unsigned char*)d_in[2];
    const float* W    = (const float*)d_in[3];
    const float* bias = (const float*)d_in[4];
    float* out = (float*)d_out;

    int* len = (int*)d_ws;                                    // 8 ints @ offset 0
    const size_t offW = 256;
    const size_t szW  = (size_t)NNT * NKT * BT_E * 2;         // 6.55 MB
    const size_t need = offW + szW;

    lengths_kernel<<<dim3(B_), dim3(256), 0, stream>>>(mask, len);

    if (ws_size >= need) {
        bf16_t* packW = (bf16_t*)((char*)d_ws + offW);
        pack_w4_kernel<<<dim3(NKT, NNT), dim3(320), 0, stream>>>(W, packW);
        gemm12_kernel<<<dim3(NMT * NNT), dim3(512), 0, stream>>>(
            fwd, rev, packW, len, bias, out);
    } else {
        profam_gemm_fallback<<<dim3(OUT_ / 128, M_ / 128), dim3(256), 0, stream>>>(
            fwd, rev, W, bias, len, out);
    }
}

// Round 9
// 140.767 us; speedup vs baseline: 1.1955x; 1.1349x over previous
//
#include <hip/hip_runtime.h>
#include <hip/hip_bf16.h>
#include <stdint.h>

// Problem constants
#define B_   8
#define S_   2048
#define D_   1280
#define OUT_ 1280
#define K_   (2 * D_)     // 2560
#define M_   (B_ * S_)    // 16384

// GEMM geometry: 256x320 tile, BK=32, 8 waves of 128x80, grid 256 (1/CU)
#define BM    256
#define BN    320
#define BK    32
#define NKT   (K_ / BK)        // 80
#define AT_E  (BM * BK)        // 8192 elems (16 KB) per A K-tile
#define BT_E  (BN * BK)        // 10240 elems (20 KB) per B K-tile
#define BUF_E (AT_E + BT_E)    // 18432 elems = 36 KB per LDS buffer
#define NMT   (M_ / BM)        // 64
#define NNT   (OUT_ / BN)      // 4

typedef __bf16 bf16_t;
typedef bf16_t bf16x8 __attribute__((ext_vector_type(8)));
typedef float  f32x4  __attribute__((ext_vector_type(4)));

// ---------------------------------------------------------------------------
// lengths: per-batch valid count (prefix mask). Handles byte or int32 storage.
// ---------------------------------------------------------------------------
__global__ void lengths_kernel(const unsigned char* __restrict__ mask,
                               int* __restrict__ len) {
    const int b = blockIdx.x;
    const bool bytefmt = (mask[1] != 0);   // lengths >= 512 so elem 1 is true
    int cnt = 0;
    if (bytefmt) {
        for (int s = threadIdx.x; s < S_; s += blockDim.x)
            cnt += (mask[(size_t)b * S_ + s] != 0) ? 1 : 0;
    } else {
        const int* mi = (const int*)mask;
        for (int s = threadIdx.x; s < S_; s += blockDim.x)
            cnt += (mi[(size_t)b * S_ + s] != 0) ? 1 : 0;
    }
    #pragma unroll
    for (int off = 32; off > 0; off >>= 1) cnt += __shfl_down(cnt, off);
    __shared__ int wsum[4];
    const int wid = threadIdx.x >> 6;
    if ((threadIdx.x & 63) == 0) wsum[wid] = cnt;
    __syncthreads();
    if (threadIdx.x == 0) len[b] = wsum[0] + wsum[1] + wsum[2] + wsum[3];
}

__device__ inline bf16x8 cvt8(float4 x, float4 y) {
    bf16x8 r;
    r[0] = (bf16_t)x.x; r[1] = (bf16_t)x.y; r[2] = (bf16_t)x.z; r[3] = (bf16_t)x.w;
    r[4] = (bf16_t)y.x; r[5] = (bf16_t)y.y; r[6] = (bf16_t)y.z; r[7] = (bf16_t)y.w;
    return r;
}

// Pack W (coalesced): [4 nt][80 kt][320r x 32k] tiles; chunk c of row r at
// slot (c ^ ((r>>1)&3)), elem offset r*32 + slot*8.
__global__ __launch_bounds__(320) void pack_w4_kernel(
    const float* __restrict__ W, bf16_t* __restrict__ packW) {
    const int kt = blockIdx.x;            // 0..79
    const int nt = blockIdx.y;            // 0..3
    const int c  = threadIdx.x & 3;
    const int r0 = threadIdx.x >> 2;      // 0..79
    const int kk = kt * BK + c * 8;
    bf16_t* dst = packW + ((size_t)nt * NKT + kt) * BT_E;
    #pragma unroll
    for (int p = 0; p < 4; ++p) {
        const int r = r0 + p * 80;
        const float* src = W + (size_t)(nt * BN + r) * K_ + kk;
        float4 x = *(const float4*)src;
        float4 y = *(const float4*)(src + 4);
        const int slot = c ^ ((r >> 1) & 3);
        *(bf16x8*)(dst + r * BK + slot * 8) = cvt8(x, y);
    }
}

// ---------------------------------------------------------------------------
// Fused GEMM, A-loads pipelined ONE FULL ITERATION ahead (round-8 fix):
// iter kt: boundary(counted vmcnt) -> issue A(kt+3)->nx -> ds_read+MFMA ->
// write-late{cvt cu=A(kt+2)->LDS, GLL B(kt+2)} -> cu<-nx. The vmem queue is
// FIFO-uniform: every wait leaves exactly {A:4 + B:3|2} younger entries ->
// counted waits (7|6), never 0, in the whole main loop. Last 3 iters peeled.
// ---------------------------------------------------------------------------
#define GLL(gp, lp) __builtin_amdgcn_global_load_lds(                        \
    (const __attribute__((address_space(1))) unsigned int*)(const void*)(gp),\
    (__attribute__((address_space(3))) unsigned int*)(void*)(lp), 16, 0, 0)

#define BOUNDARY(N3, N2)                                                     \
    asm volatile("s_waitcnt lgkmcnt(0)" ::: "memory");                       \
    if (w < 4) asm volatile("s_waitcnt vmcnt(" #N3 ")" ::: "memory");        \
    else       asm volatile("s_waitcnt vmcnt(" #N2 ")" ::: "memory");        \
    __builtin_amdgcn_s_barrier();                                            \
    __builtin_amdgcn_sched_barrier(0);

#define COMPUTE_TILE(OFF)                                                    \
    { bf16x8 af[8], bfr[5];                                                  \
      _Pragma("unroll") for (int i = 0; i < 8; ++i)                          \
          af[i] = *(const bf16x8*)&lds[(OFF) + aoff + i * 512];              \
      _Pragma("unroll") for (int j = 0; j < 5; ++j)                          \
          bfr[j] = *(const bf16x8*)&lds[(OFF) + boff + j * 512];             \
      __builtin_amdgcn_s_setprio(1);                                         \
      _Pragma("unroll") for (int i = 0; i < 8; ++i)                          \
          _Pragma("unroll") for (int j = 0; j < 5; ++j)                      \
              acc[i][j] = __builtin_amdgcn_mfma_f32_16x16x32_bf16(           \
                  af[i], bfr[j], acc[i][j], 0, 0, 0);                        \
      __builtin_amdgcn_s_setprio(0);                                         \
      __builtin_amdgcn_sched_barrier(0); }

__global__ __launch_bounds__(512, 1) void gemm13_kernel(
    const float* __restrict__ fwd, const float* __restrict__ rev,
    const bf16_t* __restrict__ pW, const int* __restrict__ len,
    const float* __restrict__ bias, float* __restrict__ out) {

    __shared__ __align__(16) bf16_t lds[3 * BUF_E];   // 108 KB

    // XCD swizzle: XCD x gets rt in [8x, 8x+8); all 4 cts of an rt-panel on
    // one XCD -> the 4x A re-read is L2-absorbed.
    const int bid = blockIdx.x;
    const int swz = (bid & 7) * 32 + (bid >> 3);
    const int rt  = swz >> 2;             // 0..63
    const int ct  = swz & 3;              // 0..3

    const int t  = threadIdx.x;
    const int l  = t & 63;
    const int w  = t >> 6;                // 0..7
    const int wmm = w >> 2;               // 0..1  (128-row group)
    const int wn  = w & 3;                // 0..3  (80-col group)

    const bf16_t* gB = pW + (size_t)ct * NKT * BT_E;
    const int l8 = l * 8;

    // ---- A gather: thread t owns row r = t>>1, k-half kh = (t&1)*16 ----
    const int r  = t >> 1;                // 0..255
    const int kh = (t & 1) * 16;
    const int m  = rt * BM + r;
    const int b  = m >> 11;
    const int s  = m & (S_ - 1);
    const int n  = len[b];
    const int ss = (s < n) ? (n - 1 - s) : s;
    const float* pf = fwd + (size_t)(b * S_ + s)  * D_;        // + kk (k < D)
    const float* pr = rev + (size_t)(b * S_ + ss) * D_ - D_;   // + kk (k >= D)
    const int swr = (r >> 1) & 3;
    const int wo0 = r * BK + (((kh >> 3) + 0) ^ swr) * 8;
    const int wo1 = r * BK + (((kh >> 3) + 1) ^ swr) * 8;

    // fragment read offsets (round-5-verified)
    const int lrow = l & 15;
    const int slot = (l >> 4) ^ ((lrow >> 1) & 3);
    const int aoff = (wmm * 128 + lrow) * BK + slot * 8;
    const int boff = AT_E + (wn * 80 + lrow) * BK + slot * 8;

    f32x4 acc[8][5] = {};
    float4 cu0, cu1, cu2, cu3, nx0, nx1, nx2, nx3;

    // ---- prologue (issue order matches steady state: B(0), A(2), B(1)) ----
    #pragma unroll
    for (int p = 0; p < 2; ++p) {         // A(0)->buf0, A(1)->buf1 (drained)
        const float* sp = pf + p * BK + kh;
        float4 x0 = *(const float4*)(sp);
        float4 x1 = *(const float4*)(sp + 4);
        float4 x2 = *(const float4*)(sp + 8);
        float4 x3 = *(const float4*)(sp + 12);
        bf16_t* dst = &lds[p * BUF_E];
        *(bf16x8*)(dst + wo0) = cvt8(x0, x1);
        *(bf16x8*)(dst + wo1) = cvt8(x2, x3);
    }
    {   // GLL B(0) -> buf0
        const int ob = 0 * BUF_E + AT_E;
        GLL(gB + (w + 0) * 512 + l8, &lds[ob + (w + 0) * 512]);
        GLL(gB + (w + 8) * 512 + l8, &lds[ob + (w + 8) * 512]);
        if (w < 4) GLL(gB + (w + 16) * 512 + l8, &lds[ob + (w + 16) * 512]);
    }
    {   // issue A(2) -> cu
        const float* sp = pf + 2 * BK + kh;
        cu0 = *(const float4*)(sp);
        cu1 = *(const float4*)(sp + 4);
        cu2 = *(const float4*)(sp + 8);
        cu3 = *(const float4*)(sp + 12);
    }
    {   // GLL B(1) -> buf1
        const bf16_t* btile = gB + BT_E;
        const int ob = BUF_E + AT_E;
        GLL(btile + (w + 0) * 512 + l8, &lds[ob + (w + 0) * 512]);
        GLL(btile + (w + 8) * 512 + l8, &lds[ob + (w + 8) * 512]);
        if (w < 4) GLL(btile + (w + 16) * 512 + l8, &lds[ob + (w + 16) * 512]);
    }

    int o0 = 0, o1 = BUF_E, o2 = 2 * BUF_E;

    // ---- main loop: kt = 0 .. NKT-4 (all issues unconditional) ----
    for (int kt = 0; kt < NKT - 3; ++kt) {
        BOUNDARY(7, 6)                    // B(kt) landed; {A(kt+2),B(kt+1)} stay

        {   // issue-early: A(kt+3) -> nx (wave-uniform branch; D_ % BK == 0)
            const int kk = (kt + 3) * BK + kh;
            const float* sp = ((kk < D_) ? pf : pr) + kk;
            nx0 = *(const float4*)(sp);
            nx1 = *(const float4*)(sp + 4);
            nx2 = *(const float4*)(sp + 8);
            nx3 = *(const float4*)(sp + 12);
        }
        __builtin_amdgcn_sched_barrier(0);

        COMPUTE_TILE(o0)

        // write-late: cvt cu = A(kt+2) -> o2 (counted wait: leaves B(kt+1)+nx)
        {
            bf16_t* dst = &lds[o2];
            *(bf16x8*)(dst + wo0) = cvt8(cu0, cu1);
            *(bf16x8*)(dst + wo1) = cvt8(cu2, cu3);
            const bf16_t* btile = gB + (size_t)(kt + 2) * BT_E;
            GLL(btile + (w + 0) * 512 + l8, &lds[o2 + AT_E + (w + 0) * 512]);
            GLL(btile + (w + 8) * 512 + l8, &lds[o2 + AT_E + (w + 8) * 512]);
            if (w < 4)
                GLL(btile + (w + 16) * 512 + l8, &lds[o2 + AT_E + (w + 16) * 512]);
        }
        cu0 = nx0; cu1 = nx1; cu2 = nx2; cu3 = nx3;

        const int tmp = o0; o0 = o1; o1 = o2; o2 = tmp;
    }

    // ---- tail kt = NKT-3: steady boundary; write A(NKT-1), GLL B(NKT-1) ----
    {
        BOUNDARY(7, 6)
        COMPUTE_TILE(o0)
        bf16_t* dst = &lds[o2];
        *(bf16x8*)(dst + wo0) = cvt8(cu0, cu1);
        *(bf16x8*)(dst + wo1) = cvt8(cu2, cu3);
        const bf16_t* btile = gB + (size_t)(NKT - 1) * BT_E;
        GLL(btile + (w + 0) * 512 + l8, &lds[o2 + AT_E + (w + 0) * 512]);
        GLL(btile + (w + 8) * 512 + l8, &lds[o2 + AT_E + (w + 8) * 512]);
        if (w < 4)
            GLL(btile + (w + 16) * 512 + l8, &lds[o2 + AT_E + (w + 16) * 512]);
        const int tmp = o0; o0 = o1; o1 = o2; o2 = tmp;
    }
    // ---- tail kt = NKT-2: queue = {B(NKT-2), B(NKT-1)} ----
    {
        BOUNDARY(3, 2)
        COMPUTE_TILE(o0)
        const int tmp = o0; o0 = o1; o1 = o2; o2 = tmp;
    }
    // ---- tail kt = NKT-1 ----
    {
        BOUNDARY(0, 0)
        COMPUTE_TILE(o0)
    }

    // ---- epilogue: C/D layout col=lane&15, row=(lane>>4)*4+v ----
    const int m0 = rt * BM + wmm * 128;
    const int n0 = ct * BN + wn * 80;
    const int r4 = (l >> 4) * 4;
    #pragma unroll
    for (int j = 0; j < 5; ++j) {
        const int col = n0 + j * 16 + lrow;
        const float bj = bias[col];
        #pragma unroll
        for (int i = 0; i < 8; ++i) {
            const int row0 = m0 + i * 16 + r4;
            #pragma unroll
            for (int v = 0; v < 4; ++v)
                out[(size_t)(row0 + v) * OUT_ + col] = acc[i][j][v] + bj;
        }
    }
}

// ---------------------------------------------------------------------------
// Fallback (round-1 kernel): used only if ws_size can't hold packed W.
// ---------------------------------------------------------------------------
#define LDKF 40
__global__ __launch_bounds__(256) void profam_gemm_fallback(
    const float* __restrict__ fwd, const float* __restrict__ rev,
    const float* __restrict__ W,   const float* __restrict__ bias,
    const int* __restrict__ len,   float* __restrict__ out) {

    __shared__ __align__(16) bf16_t lds_a[128][LDKF];
    __shared__ __align__(16) bf16_t lds_b[128][LDKF];

    const int ct = blockIdx.x;
    const int rt = blockIdx.y;
    const int m0 = rt * 128;
    const int n0 = ct * 128;
    const int t  = threadIdx.x;
    const int l  = t & 63;
    const int w  = t >> 6;
    const int wr = w >> 1, wc = w & 1;

    const int b = m0 >> 11;
    const int n = len[b];

    const int sr = t >> 1;
    const int cg = (t & 1) * 16;
    const int s  = (m0 + sr) & (S_ - 1);
    const int ss = (s < n) ? (n - 1 - s) : s;
    const float* pf = fwd + (size_t)(b * S_ + s)  * D_ + cg;
    const float* pr = rev + (size_t)(b * S_ + ss) * D_ + cg;
    const float* pw = W   + (size_t)(n0 + sr) * K_ + cg;

    f32x4 acc[4][4] = {};
    const int lrow = l & 15;
    const int kc   = (l >> 4) * 8;

    for (int kt = 0; kt < K_ / 32; ++kt) {
        const int k0 = kt * 32;
        const float* pa = (k0 < D_) ? (pf + k0) : (pr + (k0 - D_));
        const float* pb = pw + k0;
        float4 a0 = *(const float4*)(pa + 0);
        float4 a1 = *(const float4*)(pa + 4);
        float4 a2 = *(const float4*)(pa + 8);
        float4 a3 = *(const float4*)(pa + 12);
        float4 b0 = *(const float4*)(pb + 0);
        float4 b1 = *(const float4*)(pb + 4);
        float4 b2 = *(const float4*)(pb + 8);
        float4 b3 = *(const float4*)(pb + 12);
        *(bf16x8*)&lds_a[sr][cg + 0] = cvt8(a0, a1);
        *(bf16x8*)&lds_a[sr][cg + 8] = cvt8(a2, a3);
        *(bf16x8*)&lds_b[sr][cg + 0] = cvt8(b0, b1);
        *(bf16x8*)&lds_b[sr][cg + 8] = cvt8(b2, b3);
        __syncthreads();
        bf16x8 af[4], bfr[4];
        #pragma unroll
        for (int i = 0; i < 4; ++i)
            af[i] = *(const bf16x8*)&lds_a[wr * 64 + i * 16 + lrow][kc];
        #pragma unroll
        for (int j = 0; j < 4; ++j)
            bfr[j] = *(const bf16x8*)&lds_b[wc * 64 + j * 16 + lrow][kc];
        #pragma unroll
        for (int i = 0; i < 4; ++i)
            #pragma unroll
            for (int j = 0; j < 4; ++j)
                acc[i][j] = __builtin_amdgcn_mfma_f32_16x16x32_bf16(
                    af[i], bfr[j], acc[i][j], 0, 0, 0);
        __syncthreads();
    }
    #pragma unroll
    for (int j = 0; j < 4; ++j) {
        const int col = n0 + wc * 64 + j * 16 + lrow;
        const float bj = bias[col];
        #pragma unroll
        for (int i = 0; i < 4; ++i) {
            const int row0 = m0 + wr * 64 + i * 16 + (l >> 4) * 4;
            #pragma unroll
            for (int v = 0; v < 4; ++v)
                out[(size_t)(row0 + v) * OUT_ + col] = acc[i][j][v] + bj;
        }
    }
}

extern "C" void kernel_launch(void* const* d_in, const int* in_sizes, int n_in,
                              void* d_out, int out_size, void* d_ws, size_t ws_size,
                              hipStream_t stream) {
    const float* fwd  = (const float*)d_in[0];
    const float* rev  = (const float*)d_in[1];
    const unsigned char* mask = (const unsigned char*)d_in[2];
    const float* W    = (const float*)d_in[3];
    const float* bias = (const float*)d_in[4];
    float* out = (float*)d_out;

    int* len = (int*)d_ws;                                    // 8 ints @ offset 0
    const size_t offW = 256;
    const size_t szW  = (size_t)NNT * NKT * BT_E * 2;         // 6.55 MB
    const size_t need = offW + szW;

    lengths_kernel<<<dim3(B_), dim3(256), 0, stream>>>(mask, len);

    if (ws_size >= need) {
        bf16_t* packW = (bf16_t*)((char*)d_ws + offW);
        pack_w4_kernel<<<dim3(NKT, NNT), dim3(320), 0, stream>>>(W, packW);
        gemm13_kernel<<<dim3(NMT * NNT), dim3(512), 0, stream>>>(
            fwd, rev, packW, len, bias, out);
    } else {
        profam_gemm_fallback<<<dim3(OUT_ / 128, M_ / 128), dim3(256), 0, stream>>>(
            fwd, rev, W, bias, len, out);
    }
}